// Round 1
// baseline (165.947 us; speedup 1.0000x reference)
//
#include <hip/hip_runtime.h>

constexpr int HWs = 4096;   // 64*64 spatial

// ---------------------------------------------------------------------------
// Prep: fold BN into w1 (transposed), transpose w2 and wp for LDS-friendly
// GEMM staging. Tiny (132160 elements), runs every launch (deterministic).
// ---------------------------------------------------------------------------
__global__ __launch_bounds__(256) void prep_k(
    const float* __restrict__ w1, const float* __restrict__ gamma,
    const float* __restrict__ beta, const float* __restrict__ mean,
    const float* __restrict__ var, const float* __restrict__ w2,
    const float* __restrict__ wp,
    float* __restrict__ w1t, float* __restrict__ b1,
    float* __restrict__ w2t, float* __restrict__ wpt)
{
    int idx = blockIdx.x * 256 + threadIdx.x;
    if (idx < 16384) {                       // w1t[c][o] = w1[o][c]*scale[o]
        int c = idx >> 6, o = idx & 63;
        float s = gamma[o] * rsqrtf(var[o] + 1e-5f);
        w1t[idx] = w1[o * 256 + c] * s;
    } else if (idx < 16448) {                // b1[o] = beta - mean*scale
        int o = idx - 16384;
        float s = gamma[o] * rsqrtf(var[o] + 1e-5f);
        b1[o] = beta[o] - mean[o] * s;
    } else if (idx < 66624) {                // w2t[k][m] = w2[m][k]
        int i = idx - 16448;
        int k = i / 784, m = i - k * 784;
        w2t[i] = w2[m * 64 + k];
    } else if (idx < 132160) {               // wpt[c][o] = wp[o][c]
        int i = idx - 66624;
        int c = i >> 8, o = i & 255;
        wpt[i] = wp[o * 256 + c];
    }
}

// ---------------------------------------------------------------------------
// Generic 64x64-tile GEMM: Cout[b][m][hw] = sum_k At[k][m] * Bm[b][k][hw]
// 256 threads, 4x4 register block per thread, float4 LDS reads.
// ---------------------------------------------------------------------------
template<bool RELU, bool BIAS>
__global__ __launch_bounds__(256) void gemm_k(
    const float* __restrict__ At, const float* __restrict__ Bm,
    const float* __restrict__ bias, float* __restrict__ Cout,
    int K, int Mtot, int tilesPerBatch)
{
    const int t = threadIdx.x;
    const int bt = blockIdx.x;
    const int batch = bt / tilesPerBatch;
    const int n0 = (bt - batch * tilesPerBatch) * 64;
    const int m0 = blockIdx.y * 64;
    const float* Bb = Bm + (size_t)batch * K * HWs;
    float* Cb = Cout + (size_t)batch * Mtot * HWs;

    __shared__ float As[64][64];   // [k][m]
    __shared__ float Bs[64][64];   // [k][n]

    const int og = t >> 4, pg = t & 15;
    float acc[4][4];
#pragma unroll
    for (int i = 0; i < 4; ++i)
#pragma unroll
        for (int j = 0; j < 4; ++j) acc[i][j] = 0.f;

    for (int kc = 0; kc < K; kc += 64) {
#pragma unroll
        for (int r = 0; r < 16; ++r) {
            int idx = t + r * 256;
            int kk = idx >> 6, col = idx & 63;
            int m = m0 + col;
            As[kk][col] = (m < Mtot) ? At[(size_t)(kc + kk) * Mtot + m] : 0.f;
            Bs[kk][col] = Bb[(size_t)(kc + kk) * HWs + n0 + col];
        }
        __syncthreads();
#pragma unroll 8
        for (int k = 0; k < 64; ++k) {
            const float4 av = *reinterpret_cast<const float4*>(&As[k][og * 4]);
            const float4 bv = *reinterpret_cast<const float4*>(&Bs[k][pg * 4]);
            acc[0][0] += av.x * bv.x; acc[0][1] += av.x * bv.y;
            acc[0][2] += av.x * bv.z; acc[0][3] += av.x * bv.w;
            acc[1][0] += av.y * bv.x; acc[1][1] += av.y * bv.y;
            acc[1][2] += av.y * bv.z; acc[1][3] += av.y * bv.w;
            acc[2][0] += av.z * bv.x; acc[2][1] += av.z * bv.y;
            acc[2][2] += av.z * bv.z; acc[2][3] += av.z * bv.w;
            acc[3][0] += av.w * bv.x; acc[3][1] += av.w * bv.y;
            acc[3][2] += av.w * bv.z; acc[3][3] += av.w * bv.w;
        }
        __syncthreads();
    }

#pragma unroll
    for (int i = 0; i < 4; ++i) {
        int m = m0 + og * 4 + i;
        if (m < Mtot) {
            float bv = BIAS ? bias[m] : 0.f;
            float4 o4;
            o4.x = acc[i][0] + bv; o4.y = acc[i][1] + bv;
            o4.z = acc[i][2] + bv; o4.w = acc[i][3] + bv;
            if (RELU) {
                o4.x = fmaxf(o4.x, 0.f); o4.y = fmaxf(o4.y, 0.f);
                o4.z = fmaxf(o4.z, 0.f); o4.w = fmaxf(o4.w, 0.f);
            }
            *reinterpret_cast<float4*>(&Cb[(size_t)m * HWs + n0 + pg * 4]) = o4;
        }
    }
}

// ---------------------------------------------------------------------------
// Involution: out[b, g*16+ci, p] = sum_kk wt[b, g*49+kk, p] * xpatch[ci, kk, p]
// One block = (batch, group, 16x16 spatial tile). x patch staged in LDS as
// [spatial 22x22][20] (16 channels + pad 4) -> 16B-aligned float4 reads,
// stride 20 words covers all 32 banks (conflict-free b128).
// ---------------------------------------------------------------------------
__global__ __launch_bounds__(256) void inv_k(
    const float* __restrict__ x, const float* __restrict__ wt,
    float* __restrict__ out)
{
    const int t = threadIdx.x;
    const int tile = blockIdx.x;       // 16 tiles (4x4 of 16x16)
    const int g = blockIdx.y;          // 16 groups
    const int b = blockIdx.z;          // 4 batches
    const int ty0 = (tile >> 2) * 16, tx0 = (tile & 3) * 16;

    __shared__ float xs[484 * 20];     // 38720 B

    const float* xb = x + (size_t)(b * 256 + g * 16) * HWs;
    for (int idx = t; idx < 484 * 16; idx += 256) {
        int ci = idx / 484;
        int sp = idx - ci * 484;
        int sy = sp / 22, sx = sp - sy * 22;
        int gy = ty0 + sy - 3, gx = tx0 + sx - 3;
        float v = 0.f;
        if ((unsigned)gy < 64u && (unsigned)gx < 64u)
            v = xb[(size_t)ci * HWs + gy * 64 + gx];
        xs[sp * 20 + ci] = v;
    }
    __syncthreads();

    const int py = t >> 4, px = t & 15;
    float acc[16];
#pragma unroll
    for (int i = 0; i < 16; ++i) acc[i] = 0.f;

    const float* wtb = wt + (size_t)(b * 16 + g) * 49 * HWs
                          + (ty0 + py) * 64 + tx0 + px;
    for (int dy = 0; dy < 7; ++dy) {
#pragma unroll
        for (int dx = 0; dx < 7; ++dx) {
            const int kk = dy * 7 + dx;
            const float wv = wtb[(size_t)kk * HWs];
            const float* xrow = &xs[((py + dy) * 22 + px + dx) * 20];
#pragma unroll
            for (int c4 = 0; c4 < 4; ++c4) {
                const float4 xv = *reinterpret_cast<const float4*>(&xrow[c4 * 4]);
                acc[c4 * 4 + 0] += wv * xv.x;
                acc[c4 * 4 + 1] += wv * xv.y;
                acc[c4 * 4 + 2] += wv * xv.z;
                acc[c4 * 4 + 3] += wv * xv.w;
            }
        }
    }

    float* ob = out + (size_t)(b * 256 + g * 16) * HWs + (ty0 + py) * 64 + tx0 + px;
#pragma unroll
    for (int ci = 0; ci < 16; ++ci)
        ob[(size_t)ci * HWs] = acc[ci];
}

// ---------------------------------------------------------------------------
extern "C" void kernel_launch(void* const* d_in, const int* in_sizes, int n_in,
                              void* d_out, int out_size, void* d_ws, size_t ws_size,
                              hipStream_t stream)
{
    const float* x     = (const float*)d_in[0];
    const float* w1    = (const float*)d_in[1];
    const float* gamma = (const float*)d_in[2];
    const float* beta  = (const float*)d_in[3];
    const float* mean  = (const float*)d_in[4];
    const float* var   = (const float*)d_in[5];
    const float* w2    = (const float*)d_in[6];
    const float* b2    = (const float*)d_in[7];
    const float* wp    = (const float*)d_in[8];
    float* out = (float*)d_out;
    float* ws  = (float*)d_ws;

    // workspace layout (floats)
    float* w1t = ws;                 // 16384
    float* b1  = ws + 16384;         // 64
    float* w2t = ws + 16448;         // 50176
    float* wpt = ws + 66624;         // 65536
    float* y   = ws + 132160;        // 4*64*4096   = 1,048,576
    float* wtb = ws + 1180736;       // 4*784*4096  = 12,845,056
    float* inv = ws + 14025792;      // 4*256*4096  = 4,194,304
                                     // total 18,220,096 floats = 72.9 MB

    prep_k<<<517, 256, 0, stream>>>(w1, gamma, beta, mean, var, w2, wp,
                                    w1t, b1, w2t, wpt);
    // y = relu(BN(w1 @ x))
    gemm_k<true, true><<<dim3(256, 1), 256, 0, stream>>>(w1t, x, b1, y, 256, 64, 64);
    // wt = w2 @ y + b2
    gemm_k<false, true><<<dim3(256, 13), 256, 0, stream>>>(w2t, y, b2, wtb, 64, 784, 64);
    // involution
    inv_k<<<dim3(16, 16, 4), 256, 0, stream>>>(x, wtb, inv);
    // out = wp @ inv
    gemm_k<false, false><<<dim3(256, 4), 256, 0, stream>>>(wpt, inv, nullptr, out, 256, 256, 64);
}